// Round 1
// baseline (276.107 us; speedup 1.0000x reference)
//
#include <hip/hip_runtime.h>
#include <math.h>

#define KTOP 20

// ---------------------------------------------------------------------------
// Kernel 1: normalize the query row per batch into ws.  grid(B), block(64).
// ---------------------------------------------------------------------------
__global__ void qnorm_kernel(const float* __restrict__ x,
                             const int* __restrict__ qrels,
                             float* __restrict__ qn, int R) {
    int b = blockIdx.x;
    int t = threadIdx.x;                 // 0..63 == d
    int qr = qrels[b];
    float v = x[((long)b * R + qr) * 64 + t];
    float ss = v * v;
#pragma unroll
    for (int m = 1; m < 64; m <<= 1) ss += __shfl_xor(ss, m, 64);
    float dn = fmaxf(sqrtf(ss), 1e-12f);
    qn[b * 64 + t] = v / dn;
}

// ---------------------------------------------------------------------------
// Kernel 2: the HBM pass.  Copy x -> out, compute per-row cosine sim with the
// normalized query row, and the per-row L2-norm denominator.
// Each 16-lane group owns one row (64 floats) via float4 loads.
// grid(ceil(R/16), B), block(256).
// ---------------------------------------------------------------------------
__global__ void copy_sims_kernel(const float* __restrict__ x,
                                 const int* __restrict__ qrels,
                                 const float* __restrict__ qn,
                                 float* __restrict__ out,
                                 float* __restrict__ sims,
                                 float* __restrict__ dnorm, int R) {
    int b = blockIdx.y;
    int t = threadIdx.x;                 // 0..255
    int row = blockIdx.x * 16 + (t >> 4);
    int l16 = t & 15;
    if (row >= R) return;

    long base = ((long)b * R + row) * 64 + l16 * 4;
    const float4 v = *(const float4*)(x + base);
    *(float4*)(out + base) = v;

    const float4 q = *(const float4*)(qn + b * 64 + l16 * 4);
    float dot = v.x * q.x + v.y * q.y + v.z * q.z + v.w * q.w;
    float ss  = v.x * v.x + v.y * v.y + v.z * v.z + v.w * v.w;
#pragma unroll
    for (int m = 1; m < 16; m <<= 1) {
        dot += __shfl_xor(dot, m, 64);   // masks 1,2,4,8 stay inside 16-lane group
        ss  += __shfl_xor(ss,  m, 64);
    }
    if (l16 == 0) {
        float dn = fmaxf(sqrtf(ss), 1e-12f);
        int qr = qrels[b];
        sims[(long)b * R + row]  = (row == qr) ? -1.0f : dot / dn;
        dnorm[(long)b * R + row] = dn;
    }
}

// ---------------------------------------------------------------------------
// Kernel 3: per batch: top-20 (JAX tie-break: value desc, index asc), masked
// softmax + weighting, gather top rows, write the mixed query row.
// grid(B), block(256), dynamic LDS.
// ---------------------------------------------------------------------------
__global__ void finalize_kernel(const float* __restrict__ x,
                                const int* __restrict__ qrels,
                                const float* __restrict__ sims,
                                const float* __restrict__ dnorm,
                                const float* __restrict__ thr_raw,
                                const float* __restrict__ str_raw,
                                const float* __restrict__ wscale_p,
                                const float* __restrict__ temp_p,
                                float* __restrict__ out, int R) {
    extern __shared__ float smem[];
    float* s_val  = smem;                         // R
    float* red_v  = s_val + R;                    // 256
    int*   red_i  = (int*)(red_v + 256);          // 256
    float* s_topv = (float*)(red_i + 256);        // KTOP
    int*   s_topi = (int*)(s_topv + KTOP);        // KTOP
    float* s_adj  = (float*)(s_topi + KTOP);      // KTOP
    float* s_misc = s_adj + KTOP;                 // [0]=strength [1]=has_valid

    int b = blockIdx.x;
    int t = threadIdx.x;                          // 0..255

    for (int i = t; i < R; i += 256) s_val[i] = sims[(long)b * R + i];
    __syncthreads();

    // ---- iterative top-K argmax, tie -> smallest index ----
    for (int k = 0; k < KTOP; ++k) {
        float bv = -INFINITY;
        int   bi = R;
        for (int i = t; i < R; i += 256) {
            float v = s_val[i];
            if (v > bv) { bv = v; bi = i; }       // strict >: earliest index kept
        }
        red_v[t] = bv; red_i[t] = bi;
        __syncthreads();
        for (int s = 128; s > 0; s >>= 1) {
            if (t < s) {
                float v2 = red_v[t + s]; int i2 = red_i[t + s];
                if (v2 > red_v[t] || (v2 == red_v[t] && i2 < red_i[t])) {
                    red_v[t] = v2; red_i[t] = i2;
                }
            }
            __syncthreads();
        }
        if (t == 0) {
            s_topv[k] = red_v[0];
            s_topi[k] = red_i[0];
            s_val[red_i[0]] = -INFINITY;          // mask for next iteration
        }
        __syncthreads();
    }

    // ---- scalar weighting stage (20 elements) on thread 0 ----
    if (t == 0) {
        float threshold = 1.0f / (1.0f + expf(-thr_raw[0]));
        float strength  = (1.0f / (1.0f + expf(-str_raw[0]))) * 0.2f;
        float temp = fminf(fmaxf(temp_p[0], 0.1f), 10.0f);
        float wsc  = wscale_p[0];
        int   qr   = qrels[b];

        float tv[KTOP]; int ti[KTOP]; bool valid[KTOP];
        bool has_valid = false;
        float m = -INFINITY;
        for (int k = 0; k < KTOP; ++k) {
            tv[k] = s_topv[k]; ti[k] = s_topi[k];
            valid[k] = (tv[k] > threshold) && (ti[k] != qr);
            if (valid[k]) { has_valid = true; m = fmaxf(m, tv[k] / temp); }
        }
        if (has_valid) {
            float w[KTOP], wsum = 0.0f;
            for (int k = 0; k < KTOP; ++k) {
                w[k] = valid[k] ? expf(tv[k] / temp - m) : 0.0f;
                wsum += w[k];
            }
            float adj[KTOP], asum = 0.0f;
            for (int k = 0; k < KTOP; ++k) {
                float wk = w[k] / wsum;
                float sw = 1.0f / (1.0f + expf(-(tv[k] - threshold) * 10.0f));
                float a  = wk * sw * (1.0f + wsc * tv[k]);
                adj[k] = a; asum += a;
            }
            for (int k = 0; k < KTOP; ++k) {
                // fold the row-norm denominator into the weight
                float dn = dnorm[(long)b * R + ti[k]];
                s_adj[k] = (adj[k] / (asum + 1e-8f)) / dn;
            }
        } else {
            for (int k = 0; k < KTOP; ++k) s_adj[k] = 0.0f;
        }
        s_misc[0] = strength;
        s_misc[1] = has_valid ? 1.0f : 0.0f;
    }
    __syncthreads();

    // ---- vector stage: 64 lanes write the query row ----
    if (t < 64) {
        int qr = qrels[b];
        long qb = ((long)b * R + qr) * 64 + t;
        float qo = x[qb];
        float res = qo;
        if (s_misc[1] > 0.5f) {
            float acc = 0.0f;
#pragma unroll
            for (int k = 0; k < KTOP; ++k)
                acc += s_adj[k] * x[((long)b * R + s_topi[k]) * 64 + t];
            float st = s_misc[0];
            res = (1.0f - st) * qo + st * acc;
        }
        out[qb] = res;
    }
}

// ---------------------------------------------------------------------------
extern "C" void kernel_launch(void* const* d_in, const int* in_sizes, int n_in,
                              void* d_out, int out_size, void* d_ws, size_t ws_size,
                              hipStream_t stream) {
    const float* x      = (const float*)d_in[0];
    const int*   qrels  = (const int*)d_in[1];
    const float* thr    = (const float*)d_in[2];
    const float* str    = (const float*)d_in[3];
    const float* wscale = (const float*)d_in[4];
    const float* temp   = (const float*)d_in[5];
    float* out = (float*)d_out;

    const int B = in_sizes[1];
    const int D = 64;
    const int R = in_sizes[0] / (B * D);

    // workspace layout (floats): qn[B*64] | sims[B*R] | dnorm[B*R]
    float* qn    = (float*)d_ws;
    float* sims  = qn + (size_t)B * 64;
    float* dnorm = sims + (size_t)B * R;

    qnorm_kernel<<<B, 64, 0, stream>>>(x, qrels, qn, R);

    dim3 grid2((R + 15) / 16, B);
    copy_sims_kernel<<<grid2, 256, 0, stream>>>(x, qrels, qn, out, sims, dnorm, R);

    size_t shmem = (size_t)(R + 512 + 3 * KTOP + 2) * 4 + 64;
    finalize_kernel<<<B, 256, shmem, stream>>>(x, qrels, sims, dnorm,
                                               thr, str, wscale, temp, out, R);
}

// Round 2
// 253.043 us; speedup vs baseline: 1.0911x; 1.0911x over previous
//
#include <hip/hip_runtime.h>
#include <math.h>

#define KTOP 20
#define R_MAX 2048

// One block per batch. block = 1024 threads (16 waves), grid = B (256 = #CUs).
// Stage 1: stream x[b] -> out (float4, coalesced), per-row sims/norms into LDS,
//          compact candidate rows with sim > threshold (LDS atomic).
// Stage 2: wave 0 selects the top-<=20 candidates (register-resident iterative
//          argmax, JAX tie-break: value desc, index asc). Order-invariant
//          weighting math means ncand<=20 needs no sorting at all.
// Stage 3: lane 0 computes softmax/sigmoid weighting (<=20 scalars).
// Stage 4: 64 lanes gather selected rows and write the mixed query row.
__global__ __launch_bounds__(1024) void fused_enhancer(
    const float* __restrict__ x,
    const int* __restrict__ qrels,
    const float* __restrict__ thr_raw,
    const float* __restrict__ str_raw,
    const float* __restrict__ wscale_p,
    const float* __restrict__ temp_p,
    float* __restrict__ out, int R)
{
    __shared__ float s_q[64];          // normalized query row
    __shared__ float s_sims[R_MAX];    // cosine sims (self = -1)
    __shared__ float s_dn[R_MAX];      // per-row L2 norm denominators
    __shared__ int   s_cand[R_MAX];    // candidate row indices (sim > threshold)
    __shared__ int   s_ncand;
    __shared__ float s_topv[KTOP];
    __shared__ int   s_topi[KTOP];
    __shared__ float s_adj[KTOP];      // final weight / row-norm
    __shared__ float s_strength;

    const int b = blockIdx.x;
    const int t = threadIdx.x;
    const int qr = qrels[b];
    const float threshold = 1.0f / (1.0f + expf(-thr_raw[0]));

    if (t == 0) s_ncand = 0;

    // ---- stage 0: normalized query row (wave 0) ----
    if (t < 64) {
        float v = x[((long)b * R + qr) * 64 + t];
        float ss = v * v;
#pragma unroll
        for (int m = 1; m < 64; m <<= 1) ss += __shfl_xor(ss, m, 64);
        s_q[t] = v / fmaxf(sqrtf(ss), 1e-12f);
    }
    __syncthreads();

    // ---- stage 1: stream rows; 16-lane group per row, float4 per lane ----
    const int grp = t >> 4, l16 = t & 15;     // 64 groups of 16 lanes
    const float4 q4 = *(const float4*)(s_q + l16 * 4);
    const long xbase = (long)b * R * 64;
    for (int row = grp; row < R; row += 64) {  // wave covers 4 consecutive rows: 1KB coalesced
        long base = xbase + (long)row * 64 + l16 * 4;
        const float4 v = *(const float4*)(x + base);
        *(float4*)(out + base) = v;
        float dot = v.x * q4.x + v.y * q4.y + v.z * q4.z + v.w * q4.w;
        float ss  = v.x * v.x + v.y * v.y + v.z * v.z + v.w * v.w;
#pragma unroll
        for (int m = 1; m < 16; m <<= 1) {     // stays inside the 16-lane group
            dot += __shfl_xor(dot, m, 64);
            ss  += __shfl_xor(ss,  m, 64);
        }
        if (l16 == 0) {
            float dn  = fmaxf(sqrtf(ss), 1e-12f);
            float sim = (row == qr) ? -1.0f : dot / dn;
            s_sims[row] = sim;
            s_dn[row]   = dn;
            if (sim > threshold) {
                int p = atomicAdd(&s_ncand, 1);
                s_cand[p] = row;
            }
        }
    }
    __syncthreads();

    const int ncand = s_ncand;
    const int ksel = ncand < KTOP ? ncand : KTOP;

    // ---- stage 2: selection ----
    if (t < 64) {
        if (ncand > KTOP) {
            // register-resident iterative argmax over candidates, wave 0 only
            float lv[32]; int li[32];
#pragma unroll
            for (int j = 0; j < 32; ++j) {
                int i = t + 64 * j;
                if (i < ncand) { li[j] = s_cand[i]; lv[j] = s_sims[li[j]]; }
                else           { li[j] = 0x7fffffff; lv[j] = -INFINITY; }
            }
            for (int k = 0; k < KTOP; ++k) {
                float bv = -INFINITY; int bi = 0x7fffffff;
#pragma unroll
                for (int j = 0; j < 32; ++j) {
                    if (lv[j] > bv || (lv[j] == bv && li[j] < bi)) { bv = lv[j]; bi = li[j]; }
                }
#pragma unroll
                for (int m = 1; m < 64; m <<= 1) {    // butterfly: all lanes end with winner
                    float v2 = __shfl_xor(bv, m, 64);
                    int   i2 = __shfl_xor(bi, m, 64);
                    if (v2 > bv || (v2 == bv && i2 < bi)) { bv = v2; bi = i2; }
                }
#pragma unroll
                for (int j = 0; j < 32; ++j) if (li[j] == bi) lv[j] = -INFINITY;
                if (t == 0) { s_topv[k] = bv; s_topi[k] = bi; }
            }
        } else if (t == 0) {
            // <=20 candidates: the selected set IS the candidate set (weighting
            // is order-invariant, no sort needed)
            for (int k = 0; k < ksel; ++k) {
                int idx = s_cand[k];
                s_topi[k] = idx;
                s_topv[k] = s_sims[idx];
            }
        }
    }

    // ---- stage 3: scalar weighting on lane 0 (all selected entries valid) ----
    if (t == 0) {
        float strength = (1.0f / (1.0f + expf(-str_raw[0]))) * 0.2f;
        float temp = fminf(fmaxf(temp_p[0], 0.1f), 10.0f);
        float wsc  = wscale_p[0];
        if (ksel > 0) {
            float m = -INFINITY;
            for (int k = 0; k < ksel; ++k) m = fmaxf(m, s_topv[k] / temp);
            float w[KTOP]; float wsum = 0.0f;
            for (int k = 0; k < ksel; ++k) { w[k] = expf(s_topv[k] / temp - m); wsum += w[k]; }
            float adj[KTOP]; float asum = 0.0f;
            for (int k = 0; k < ksel; ++k) {
                float tv = s_topv[k];
                float sw = 1.0f / (1.0f + expf(-(tv - threshold) * 10.0f));
                float a  = (w[k] / wsum) * sw * (1.0f + wsc * tv);
                adj[k] = a; asum += a;
            }
            for (int k = 0; k < ksel; ++k)
                s_adj[k] = (adj[k] / (asum + 1e-8f)) / s_dn[s_topi[k]];
        }
        s_strength = strength;
    }
    __syncthreads();

    // ---- stage 4: write mixed query row (64 lanes) ----
    if (t < 64 && ksel > 0) {
        long qb = ((long)b * R + qr) * 64 + t;
        float qo = x[qb];
        float acc = 0.0f;
        for (int k = 0; k < ksel; ++k)
            acc += s_adj[k] * x[((long)b * R + s_topi[k]) * 64 + t];
        float st = s_strength;
        out[qb] = (1.0f - st) * qo + st * acc;
        // ksel==0: streaming already wrote the original row -> matches reference
    }
}

extern "C" void kernel_launch(void* const* d_in, const int* in_sizes, int n_in,
                              void* d_out, int out_size, void* d_ws, size_t ws_size,
                              hipStream_t stream) {
    const float* x      = (const float*)d_in[0];
    const int*   qrels  = (const int*)d_in[1];
    const float* thr    = (const float*)d_in[2];
    const float* str    = (const float*)d_in[3];
    const float* wscale = (const float*)d_in[4];
    const float* temp   = (const float*)d_in[5];
    float* out = (float*)d_out;

    const int B = in_sizes[1];
    const int D = 64;
    const int R = in_sizes[0] / (B * D);
    (void)D; (void)d_ws; (void)ws_size;

    fused_enhancer<<<B, 1024, 0, stream>>>(x, qrels, thr, str, wscale, temp, out, R);
}